// Round 3
// baseline (196.727 us; speedup 1.0000x reference)
//
#include <hip/hip_runtime.h>
#include <hip/hip_bf16.h>

#define HW_ (512 * 512)
#define STEP_ (6.28318530717958647692f / 512.0f)

typedef __attribute__((ext_vector_type(8))) _Float16 half8;
typedef __attribute__((ext_vector_type(4))) float    f32x4;

// ---------------- K1: fused gray + w-FFT, no LDS, on-the-fly basis ---------
// P[b][row][h]: row<64 -> cos part (Pc), row>=64 -> MINUS sin part (-Ps).
__global__ __launch_bounds__(256) void k1(const float* __restrict__ x,
                                          _Float16* __restrict__ P)
{
    int h0 = blockIdx.x * 32;                // 16 h-tiles of 32 rows
    int b  = blockIdx.y;
    int t  = threadIdx.x;
    int lane = t & 63, wv = t >> 6, l15 = lane & 15, quad = lane >> 4;
    const float* xb = x + (size_t)b * 3 * HW_;

    f32x4 acc[2][2];
    for (int i = 0; i < 2; ++i)
        for (int j = 0; j < 2; ++j) acc[i][j] = (f32x4){0.f, 0.f, 0.f, 0.f};

    int  r6[2];
    bool issin[2];
    for (int mi = 0; mi < 2; ++mi) {
        int row = wv * 32 + mi * 16 + l15;   // basis row 0..127
        r6[mi]    = row & 63;
        issin[mi] = row >= 64;
    }

    for (int k0 = 0; k0 < 512; k0 += 32) {   // k = w
        int kc = k0 + quad * 8;

        // A fragments: cos/sin(2*pi*(r6*k)/512), computed in-register
        half8 a[2];
        for (int mi = 0; mi < 2; ++mi)
            for (int j = 0; j < 8; ++j) {
                int ph = (r6[mi] * (kc + j)) & 511;
                float ang = (float)ph * STEP_;
                a[mi][j] = (_Float16)(issin[mi] ? __sinf(ang) : __cosf(ang));
            }

        // B fragments: grayscale straight from global (zero reuse -> no LDS)
        half8 bv[2];
        for (int ni = 0; ni < 2; ++ni) {
            const float* p = xb + (size_t)(h0 + ni * 16 + l15) * 512 + kc;
            float4 r0 = *(const float4*)p;
            float4 r1 = *(const float4*)(p + 4);
            float4 g0 = *(const float4*)(p + HW_);
            float4 g1 = *(const float4*)(p + HW_ + 4);
            float4 b0 = *(const float4*)(p + 2 * HW_);
            float4 b1 = *(const float4*)(p + 2 * HW_ + 4);
            bv[ni][0] = (_Float16)(0.299f * r0.x + 0.587f * g0.x + 0.114f * b0.x);
            bv[ni][1] = (_Float16)(0.299f * r0.y + 0.587f * g0.y + 0.114f * b0.y);
            bv[ni][2] = (_Float16)(0.299f * r0.z + 0.587f * g0.z + 0.114f * b0.z);
            bv[ni][3] = (_Float16)(0.299f * r0.w + 0.587f * g0.w + 0.114f * b0.w);
            bv[ni][4] = (_Float16)(0.299f * r1.x + 0.587f * g1.x + 0.114f * b1.x);
            bv[ni][5] = (_Float16)(0.299f * r1.y + 0.587f * g1.y + 0.114f * b1.y);
            bv[ni][6] = (_Float16)(0.299f * r1.z + 0.587f * g1.z + 0.114f * b1.z);
            bv[ni][7] = (_Float16)(0.299f * r1.w + 0.587f * g1.w + 0.114f * b1.w);
        }

        for (int mi = 0; mi < 2; ++mi)
            for (int ni = 0; ni < 2; ++ni)
                acc[mi][ni] = __builtin_amdgcn_mfma_f32_16x16x32_f16(
                    a[mi], bv[ni], acc[mi][ni], 0, 0, 0);
    }

    _Float16* Pb = P + (size_t)b * 128 * 512;
    for (int mi = 0; mi < 2; ++mi)
        for (int ni = 0; ni < 2; ++ni)
            for (int r = 0; r < 4; ++r) {
                int m = wv * 32 + mi * 16 + quad * 4 + r;
                int h = h0 + ni * 16 + l15;
                float v = acc[mi][ni][r];
                if (m >= 64) v = -v;                       // fold -sin
                Pb[m * 512 + h] = (_Float16)v;
            }
}

// ---------------- K2: h-FFT, on-the-fly basis.  X scaled by 1/16 -----------
__global__ __launch_bounds__(128) void k2(const _Float16* __restrict__ P,
                                          _Float16* __restrict__ X)
{
    int b     = blockIdx.y;
    int mbase = blockIdx.x * 32 + (threadIdx.x >> 6) * 16;  // kh tile
    int lane  = threadIdx.x & 63, l15 = lane & 15, quad = lane >> 4;

    f32x4 acc[4];
    for (int i = 0; i < 4; ++i) acc[i] = (f32x4){0.f, 0.f, 0.f, 0.f};

    const _Float16* Pb = P + (size_t)b * 128 * 512;
    int rm = mbase + l15;                    // kh row, 0..63

    for (int k0 = 0; k0 < 1024; k0 += 32) {
        int kc   = k0 + quad * 8;
        bool iss = kc >= 512;                // uniform per k0 step? per quad!
        int col  = kc & 511;
        int hi   = iss ? 64 : 0;

        half8 a;
        for (int j = 0; j < 8; ++j) {
            int ph = (rm * (col + j)) & 511;
            float ang = (float)ph * STEP_;
            a[j] = (_Float16)(iss ? __sinf(ang) : __cosf(ang));
        }
        for (int ni = 0; ni < 4; ++ni) {
            half8 bv = *(const half8*)(Pb + (size_t)(hi + ni * 16 + l15) * 512 + col);
            acc[ni] = __builtin_amdgcn_mfma_f32_16x16x32_f16(a, bv, acc[ni], 0, 0, 0);
        }
    }

    _Float16* Xb = X + (size_t)b * 4096;
    for (int ni = 0; ni < 4; ++ni)
        for (int r = 0; r < 4; ++r) {
            int kh = mbase + quad * 4 + r;
            int kw = ni * 16 + l15;
            Xb[kh * 64 + kw] = (_Float16)(acc[ni][r] * 0.0625f);  // fit f16
        }
}

// ---------------- K3: FC, split-K across 4 waves + LDS reduce, no atomics --
__global__ __launch_bounds__(256) void k3(const _Float16* __restrict__ X,
                                          const float* __restrict__ fc_w,
                                          const float* __restrict__ fc_b,
                                          float* __restrict__ out)
{
    __shared__ float part[4][32][16];
    int nb = blockIdx.x;                     // feature tile of 16
    int t  = threadIdx.x;
    int lane = t & 63, wv = t >> 6, l15 = lane & 15, quad = lane >> 4;

    f32x4 acc[2];
    acc[0] = (f32x4){0.f, 0.f, 0.f, 0.f};
    acc[1] = (f32x4){0.f, 0.f, 0.f, 0.f};

    int kbeg = wv * 1024;
    for (int k0 = kbeg; k0 < kbeg + 1024; k0 += 32) {
        int kk = k0 + quad * 8;
        half8 a0 = *(const half8*)(X + (size_t)l15 * 4096 + kk);
        half8 a1 = *(const half8*)(X + (size_t)(16 + l15) * 4096 + kk);
        const float* wp = fc_w + (size_t)(nb * 16 + l15) * 4096 + kk;
        float4 f0 = *(const float4*)wp;
        float4 f1 = *(const float4*)(wp + 4);
        half8 b0;
        b0[0] = (_Float16)(f0.x * 16.0f);
        b0[1] = (_Float16)(f0.y * 16.0f);
        b0[2] = (_Float16)(f0.z * 16.0f);
        b0[3] = (_Float16)(f0.w * 16.0f);
        b0[4] = (_Float16)(f1.x * 16.0f);
        b0[5] = (_Float16)(f1.y * 16.0f);
        b0[6] = (_Float16)(f1.z * 16.0f);
        b0[7] = (_Float16)(f1.w * 16.0f);
        acc[0] = __builtin_amdgcn_mfma_f32_16x16x32_f16(a0, b0, acc[0], 0, 0, 0);
        acc[1] = __builtin_amdgcn_mfma_f32_16x16x32_f16(a1, b0, acc[1], 0, 0, 0);
    }

    for (int mi = 0; mi < 2; ++mi)
        for (int r = 0; r < 4; ++r)
            part[wv][mi * 16 + quad * 4 + r][l15] = acc[mi][r];
    __syncthreads();

    for (int e = 0; e < 2; ++e) {
        int o = t + e * 256;                 // 512 outputs per block
        int m = o >> 4, fi = o & 15;
        float v = part[0][m][fi] + part[1][m][fi] + part[2][m][fi] + part[3][m][fi]
                + fc_b[nb * 16 + fi];
        out[m * 256 + nb * 16 + fi] = v;
    }
}

// ---------------------------------------------------------------------------
extern "C" void kernel_launch(void* const* d_in, const int* in_sizes, int n_in,
                              void* d_out, int out_size, void* d_ws, size_t ws_size,
                              hipStream_t stream) {
    const float* x    = (const float*)d_in[0];
    const float* fc_w = (const float*)d_in[1];
    const float* fc_b = (const float*)d_in[2];
    float* out = (float*)d_out;

    char* ws = (char*)d_ws;
    _Float16* P = (_Float16*)(ws + 0);        // 32*128*512*2 = 4194304
    _Float16* X = (_Float16*)(ws + 4194304);  // 32*4096*2    = 262144

    k1<<<dim3(16, 32), 256, 0, stream>>>(x, P);
    k2<<<dim3(2, 32), 128, 0, stream>>>(P, X);
    k3<<<16, 256, 0, stream>>>(X, fc_w, fc_b, out);
}

// Round 4
// 195.829 us; speedup vs baseline: 1.0046x; 1.0046x over previous
//
#include <hip/hip_runtime.h>
#include <hip/hip_bf16.h>

#define HW_ (512 * 512)

typedef __attribute__((ext_vector_type(8))) _Float16 half8;
typedef __attribute__((ext_vector_type(4))) _Float16 half4;
typedef __attribute__((ext_vector_type(4))) float    f32x4;

// ---------------- K0: basis table [128][512], rows 0..63 cos, 64..127 sin --
__global__ __launch_bounds__(256) void k_prep(_Float16* __restrict__ basisA) {
    int i = blockIdx.x * 256 + threadIdx.x;   // 256 blocks -> 65536
    if (i < 128 * 512) {
        int r = i >> 9, h = i & 511;
        int ph = ((r & 63) * h) & 511;
        float ang = (float)ph * (6.28318530717958647692f / 512.0f);
        basisA[i] = (_Float16)((r < 64) ? cosf(ang) : sinf(ang));
    }
}

// ---------------- K1: fused gray + w-FFT (LDS staging, coalesced reads) ----
// P[b][row][h]: row<64 -> cos part (Pc), row>=64 -> MINUS sin part (-Ps).
__global__ __launch_bounds__(256) void k1(const float* __restrict__ x,
                                          const _Float16* __restrict__ basisA,
                                          _Float16* __restrict__ P)
{
    __shared__ _Float16 g[32][520];          // +8 halfs pad: 2-way reads free
    int h0 = blockIdx.x * 32;                // 16 h-tiles
    int b  = blockIdx.y;
    int t  = threadIdx.x;
    const float* xb = x + (size_t)b * 3 * HW_;

    // stage gray slab [32 h][512 w]; consecutive lanes -> consecutive float4
    for (int i = 0; i < 16; ++i) {
        int slot = t + i * 256;
        int hh = slot >> 7;                  // 0..31
        int w4 = slot & 127;                 // float4 index along w
        const float* p = xb + (size_t)(h0 + hh) * 512 + w4 * 4;
        float4 r  = *(const float4*)p;
        float4 gg = *(const float4*)(p + HW_);
        float4 bb = *(const float4*)(p + 2 * HW_);
        half4 o;
        o.x = (_Float16)(0.299f * r.x + 0.587f * gg.x + 0.114f * bb.x);
        o.y = (_Float16)(0.299f * r.y + 0.587f * gg.y + 0.114f * bb.y);
        o.z = (_Float16)(0.299f * r.z + 0.587f * gg.z + 0.114f * bb.z);
        o.w = (_Float16)(0.299f * r.w + 0.587f * gg.w + 0.114f * bb.w);
        *(half4*)&g[hh][w4 * 4] = o;
    }
    __syncthreads();

    int lane = t & 63, wv = t >> 6, l15 = lane & 15, quad = lane >> 4;
    f32x4 acc[2][2];
    for (int i = 0; i < 2; ++i)
        for (int j = 0; j < 2; ++j) acc[i][j] = (f32x4){0.f, 0.f, 0.f, 0.f};

    for (int k0 = 0; k0 < 512; k0 += 32) {   // k = w
        int kc = k0 + quad * 8;
        half8 a[2], bv[2];
        for (int mi = 0; mi < 2; ++mi)
            a[mi] = *(const half8*)(basisA + (wv * 32 + mi * 16 + l15) * 512 + kc);
        for (int ni = 0; ni < 2; ++ni)
            bv[ni] = *(const half8*)&g[ni * 16 + l15][kc];
        for (int mi = 0; mi < 2; ++mi)
            for (int ni = 0; ni < 2; ++ni)
                acc[mi][ni] = __builtin_amdgcn_mfma_f32_16x16x32_f16(
                    a[mi], bv[ni], acc[mi][ni], 0, 0, 0);
    }

    _Float16* Pb = P + (size_t)b * 128 * 512;
    for (int mi = 0; mi < 2; ++mi)
        for (int ni = 0; ni < 2; ++ni)
            for (int r = 0; r < 4; ++r) {
                int m = wv * 32 + mi * 16 + quad * 4 + r;
                int h = h0 + ni * 16 + l15;
                float v = acc[mi][ni][r];
                if (m >= 64) v = -v;                       // fold -sin
                Pb[m * 512 + h] = (_Float16)v;
            }
}

// ---------------- K2: h-FFT via basis table.  X scaled by 1/16 -------------
__global__ __launch_bounds__(128) void k2(const _Float16* __restrict__ basisA,
                                          const _Float16* __restrict__ P,
                                          _Float16* __restrict__ X)
{
    int b     = blockIdx.y;
    int mbase = blockIdx.x * 32 + (threadIdx.x >> 6) * 16;  // kh tile
    int lane  = threadIdx.x & 63, l15 = lane & 15, quad = lane >> 4;

    f32x4 acc[4];
    for (int i = 0; i < 4; ++i) acc[i] = (f32x4){0.f, 0.f, 0.f, 0.f};

    const _Float16* Pb = P + (size_t)b * 128 * 512;

    for (int k0 = 0; k0 < 1024; k0 += 32) {
        int kc  = k0 + quad * 8;
        int hi  = (kc >= 512) ? 64 : 0;
        int col = kc & 511;
        half8 a = *(const half8*)(basisA + (size_t)(hi + mbase + l15) * 512 + col);
        for (int ni = 0; ni < 4; ++ni) {
            half8 bv = *(const half8*)(Pb + (size_t)(hi + ni * 16 + l15) * 512 + col);
            acc[ni] = __builtin_amdgcn_mfma_f32_16x16x32_f16(a, bv, acc[ni], 0, 0, 0);
        }
    }

    _Float16* Xb = X + (size_t)b * 4096;
    for (int ni = 0; ni < 4; ++ni)
        for (int r = 0; r < 4; ++r) {
            int kh = mbase + quad * 4 + r;
            int kw = ni * 16 + l15;
            Xb[kh * 64 + kw] = (_Float16)(acc[ni][r] * 0.0625f);  // fit f16
        }
}

// ---------------- K3: FC, split-K across 4 waves + LDS reduce, no atomics --
__global__ __launch_bounds__(256) void k3(const _Float16* __restrict__ X,
                                          const float* __restrict__ fc_w,
                                          const float* __restrict__ fc_b,
                                          float* __restrict__ out)
{
    __shared__ float part[4][32][16];
    int nb = blockIdx.x;                     // feature tile of 16
    int t  = threadIdx.x;
    int lane = t & 63, wv = t >> 6, l15 = lane & 15, quad = lane >> 4;

    f32x4 acc[2];
    acc[0] = (f32x4){0.f, 0.f, 0.f, 0.f};
    acc[1] = (f32x4){0.f, 0.f, 0.f, 0.f};

    int kbeg = wv * 1024;
    for (int k0 = kbeg; k0 < kbeg + 1024; k0 += 32) {
        int kk = k0 + quad * 8;
        half8 a0 = *(const half8*)(X + (size_t)l15 * 4096 + kk);
        half8 a1 = *(const half8*)(X + (size_t)(16 + l15) * 4096 + kk);
        const float* wp = fc_w + (size_t)(nb * 16 + l15) * 4096 + kk;
        float4 f0 = *(const float4*)wp;
        float4 f1 = *(const float4*)(wp + 4);
        half8 b0;
        b0[0] = (_Float16)(f0.x * 16.0f);
        b0[1] = (_Float16)(f0.y * 16.0f);
        b0[2] = (_Float16)(f0.z * 16.0f);
        b0[3] = (_Float16)(f0.w * 16.0f);
        b0[4] = (_Float16)(f1.x * 16.0f);
        b0[5] = (_Float16)(f1.y * 16.0f);
        b0[6] = (_Float16)(f1.z * 16.0f);
        b0[7] = (_Float16)(f1.w * 16.0f);
        acc[0] = __builtin_amdgcn_mfma_f32_16x16x32_f16(a0, b0, acc[0], 0, 0, 0);
        acc[1] = __builtin_amdgcn_mfma_f32_16x16x32_f16(a1, b0, acc[1], 0, 0, 0);
    }

    for (int mi = 0; mi < 2; ++mi)
        for (int r = 0; r < 4; ++r)
            part[wv][mi * 16 + quad * 4 + r][l15] = acc[mi][r];
    __syncthreads();

    for (int e = 0; e < 2; ++e) {
        int o = t + e * 256;                 // 512 outputs per block
        int m = o >> 4, fi = o & 15;
        float v = part[0][m][fi] + part[1][m][fi] + part[2][m][fi] + part[3][m][fi]
                + fc_b[nb * 16 + fi];
        out[m * 256 + nb * 16 + fi] = v;
    }
}

// ---------------------------------------------------------------------------
extern "C" void kernel_launch(void* const* d_in, const int* in_sizes, int n_in,
                              void* d_out, int out_size, void* d_ws, size_t ws_size,
                              hipStream_t stream) {
    const float* x    = (const float*)d_in[0];
    const float* fc_w = (const float*)d_in[1];
    const float* fc_b = (const float*)d_in[2];
    float* out = (float*)d_out;

    char* ws = (char*)d_ws;
    _Float16* basisA = (_Float16*)(ws + 0);          // 128*512*2    = 131072
    _Float16* P      = (_Float16*)(ws + 131072);     // 32*128*512*2 = 4194304
    _Float16* X      = (_Float16*)(ws + 4325376);    // 32*4096*2    = 262144

    k_prep<<<256, 256, 0, stream>>>(basisA);
    k1<<<dim3(16, 32), 256, 0, stream>>>(x, basisA, P);
    k2<<<dim3(2, 32), 128, 0, stream>>>(basisA, P, X);
    k3<<<16, 256, 0, stream>>>(X, fc_w, fc_b, out);
}